// Round 1
// baseline (6080.455 us; speedup 1.0000x reference)
//
#include <hip/hip_runtime.h>

#define N_NODES 100000
#define N_EDGES 1600000
#define E_TOT   (N_EDGES + N_NODES)   // edges + self-loops
#define NUM_G   4096
#define HID     128
#define F_IN    11
#define F_OUT   19

// ---------------- degree / normalization ----------------
__global__ void init_deg(float* __restrict__ deg) {
    int i = blockIdx.x * blockDim.x + threadIdx.x;
    if (i < N_NODES) deg[i] = 1.0f;            // self-loop contributes 1
}

__global__ void accum_deg(const int* __restrict__ dst, float* __restrict__ deg) {
    int e = blockIdx.x * blockDim.x + threadIdx.x;
    if (e < N_EDGES) atomicAdd(&deg[dst[e]], 1.0f);
}

__global__ void rsqrt_deg(float* __restrict__ deg) {
    int i = blockIdx.x * blockDim.x + threadIdx.x;
    if (i < N_NODES) deg[i] = rsqrtf(deg[i]);
}

// ---------------- x @ W1 -> A [N, HID] ----------------
__global__ void gemm_xw1(const float* __restrict__ x, const float* __restrict__ W1,
                         float* __restrict__ A) {
    __shared__ float xs[F_IN];
    int v = blockIdx.x;
    int j = threadIdx.x;                        // 0..127
    if (j < F_IN) xs[j] = x[v * F_IN + j];
    __syncthreads();
    float acc = 0.f;
#pragma unroll
    for (int k = 0; k < F_IN; ++k) acc += xs[k] * W1[k * HID + j];
    A[v * HID + j] = acc;
}

// ---------------- edge scatter: B[dst] += A[src] * dinv[src]*dinv[dst] ----------------
// 32 threads per edge, one float4 (4 feats) per thread.
__global__ void scatter_edges(const int* __restrict__ src, const int* __restrict__ dst,
                              const float* __restrict__ dinv, const float* __restrict__ A,
                              float* __restrict__ B) {
    int tid = blockIdx.x * blockDim.x + threadIdx.x;
    int e   = tid >> 5;
    int f4  = tid & 31;                         // float4 index 0..31
    if (e >= E_TOT) return;
    int s, d;
    if (e < N_EDGES) { s = src[e]; d = dst[e]; }
    else             { s = d = e - N_EDGES; }   // self-loop
    float norm = dinv[s] * dinv[d];
    const float4* arow = (const float4*)(A + (size_t)s * HID);
    float4 val = arow[f4];
    float* brow = B + (size_t)d * HID + f4 * 4;
    atomicAdd(brow + 0, val.x * norm);
    atomicAdd(brow + 1, val.y * norm);
    atomicAdd(brow + 2, val.z * norm);
    atomicAdd(brow + 3, val.w * norm);
}

// ---------------- bias + relu in place ----------------
__global__ void bias_relu(float* __restrict__ B, const float* __restrict__ b) {
    int i = blockIdx.x * blockDim.x + threadIdx.x;
    if (i < N_NODES * HID) {
        float v = B[i] + b[i & (HID - 1)];
        B[i] = v > 0.f ? v : 0.f;
    }
}

// ---------------- B @ W2 -> A [N, HID] ----------------
__global__ void gemm_w2(const float* __restrict__ Bm, const float* __restrict__ W2,
                        float* __restrict__ A) {
    __shared__ float row[HID];
    int v = blockIdx.x;
    int j = threadIdx.x;
    row[j] = Bm[v * HID + j];
    __syncthreads();
    float acc = 0.f;
#pragma unroll 8
    for (int k = 0; k < HID; ++k) acc += row[k] * W2[k * HID + j];
    A[v * HID + j] = acc;
}

// ---------------- mean-pool accumulate: pooled[batch[v]] += B[v] + b2 ----------------
__global__ void pool_accum(const float* __restrict__ B, const float* __restrict__ b2,
                           const int* __restrict__ batch, float* __restrict__ pooled,
                           float* __restrict__ cnts) {
    int i = blockIdx.x * blockDim.x + threadIdx.x;
    if (i >= N_NODES * HID) return;
    int v = i >> 7;
    int f = i & (HID - 1);
    int g = batch[v];
    atomicAdd(&pooled[g * HID + f], B[i] + b2[f]);
    if (f == 0) atomicAdd(&cnts[g], 1.0f);
}

// ---------------- head: out = (pooled/cnt) @ Wlin + blin ----------------
__global__ void head_k(const float* __restrict__ pooled, const float* __restrict__ cnts,
                       const float* __restrict__ Wlin, const float* __restrict__ blin,
                       float* __restrict__ out) {
    int i = blockIdx.x * blockDim.x + threadIdx.x;
    if (i >= NUM_G * F_OUT) return;
    int g = i / F_OUT;
    int o = i - g * F_OUT;
    float c = cnts[g];
    c = c > 1.f ? c : 1.f;
    float acc = 0.f;
#pragma unroll 8
    for (int k = 0; k < HID; ++k) acc += pooled[g * HID + k] * Wlin[k * F_OUT + o];
    out[i] = acc / c + blin[o];
}

extern "C" void kernel_launch(void* const* d_in, const int* in_sizes, int n_in,
                              void* d_out, int out_size, void* d_ws, size_t ws_size,
                              hipStream_t stream) {
    const float* x    = (const float*)d_in[0];
    const int*   esrc = (const int*)  d_in[1];
    const int*   edst = (const int*)  d_in[2];
    const int*   batch= (const int*)  d_in[3];
    const float* W1   = (const float*)d_in[4];
    const float* b1   = (const float*)d_in[5];
    const float* W2   = (const float*)d_in[6];
    const float* b2   = (const float*)d_in[7];
    const float* Wlin = (const float*)d_in[8];
    const float* blin = (const float*)d_in[9];
    float* out = (float*)d_out;

    float* ws     = (float*)d_ws;
    float* dinv   = ws;                                    // N
    float* A      = dinv + N_NODES;                        // N*HID (16B aligned: 400000 % 16 == 0)
    float* B      = A + (size_t)N_NODES * HID;             // N*HID
    float* pooled = B + (size_t)N_NODES * HID;             // NUM_G*HID
    float* cnts   = pooled + (size_t)NUM_G * HID;          // NUM_G

    // 1. normalization coefficients
    init_deg<<<(N_NODES + 255) / 256, 256, 0, stream>>>(dinv);
    accum_deg<<<(N_EDGES + 255) / 256, 256, 0, stream>>>(edst, dinv);
    rsqrt_deg<<<(N_NODES + 255) / 256, 256, 0, stream>>>(dinv);

    // 2. layer 1
    gemm_xw1<<<N_NODES, HID, 0, stream>>>(x, W1, A);
    hipMemsetAsync(B, 0, (size_t)N_NODES * HID * sizeof(float), stream);
    {
        int threads = E_TOT * 32;
        scatter_edges<<<(threads + 255) / 256, 256, 0, stream>>>(esrc, edst, dinv, A, B);
    }
    bias_relu<<<(N_NODES * HID + 255) / 256, 256, 0, stream>>>(B, b1);

    // 3. layer 2
    gemm_w2<<<N_NODES, HID, 0, stream>>>(B, W2, A);
    hipMemsetAsync(B, 0, (size_t)N_NODES * HID * sizeof(float), stream);
    {
        int threads = E_TOT * 32;
        scatter_edges<<<(threads + 255) / 256, 256, 0, stream>>>(esrc, edst, dinv, A, B);
    }

    // 4. mean pool (+b2 folded in) and linear head
    hipMemsetAsync(pooled, 0, (size_t)(NUM_G * HID + NUM_G) * sizeof(float), stream);
    pool_accum<<<(N_NODES * HID + 255) / 256, 256, 0, stream>>>(B, b2, batch, pooled, cnts);
    head_k<<<(NUM_G * F_OUT + 255) / 256, 256, 0, stream>>>(pooled, cnts, Wlin, blin, out);
}

// Round 2
// 856.836 us; speedup vs baseline: 7.0964x; 7.0964x over previous
//
#include <hip/hip_runtime.h>

#define N_NODES 100000
#define N_EDGES 1600000
#define NUM_G   4096
#define HID     128
#define F_IN    11
#define F_OUT   19
#define SCAN_B  1024

// ---------------- degree count (in-degree on dst; self-loop added analytically) ----------------
__global__ void count_deg(const int* __restrict__ dst, int* __restrict__ cnt) {
    int e = blockIdx.x * blockDim.x + threadIdx.x;
    if (e < N_EDGES) atomicAdd(&cnt[dst[e]], 1);
}

__global__ void make_dinv(const int* __restrict__ cnt, float* __restrict__ dinv) {
    int i = blockIdx.x * blockDim.x + threadIdx.x;
    if (i < N_NODES) dinv[i] = rsqrtf(1.0f + (float)cnt[i]);   // +1 = self-loop
}

// ---------------- exclusive scan of cnt -> row_ptr (3-pass) ----------------
__global__ void scan1(const int* __restrict__ cnt, int* __restrict__ row_ptr,
                      int* __restrict__ bsum) {
    __shared__ int tmp[SCAN_B];
    int i = blockIdx.x * SCAN_B + threadIdx.x;
    int v = (i < N_NODES) ? cnt[i] : 0;
    tmp[threadIdx.x] = v;
    __syncthreads();
    for (int off = 1; off < SCAN_B; off <<= 1) {
        int t = (threadIdx.x >= (unsigned)off) ? tmp[threadIdx.x - off] : 0;
        __syncthreads();
        tmp[threadIdx.x] += t;
        __syncthreads();
    }
    if (i < N_NODES) row_ptr[i] = tmp[threadIdx.x] - v;        // block-local exclusive
    if (threadIdx.x == SCAN_B - 1) bsum[blockIdx.x] = tmp[SCAN_B - 1];
}

__global__ void scan2(int* __restrict__ bsum, int nb) {
    if (threadIdx.x == 0 && blockIdx.x == 0) {
        int run = 0;
        for (int i = 0; i < nb; ++i) { int t = bsum[i]; bsum[i] = run; run += t; }
    }
}

__global__ void scan3(int* __restrict__ row_ptr, const int* __restrict__ bsum,
                      int* __restrict__ cursor) {
    int i = blockIdx.x * blockDim.x + threadIdx.x;
    if (i < N_NODES) {
        int rp = row_ptr[i] + bsum[i / SCAN_B];
        row_ptr[i] = rp;
        cursor[i]  = rp;
    }
    if (i == 0) row_ptr[N_NODES] = N_EDGES;
}

// ---------------- CSR fill: col[pos] = src, bucketed by dst ----------------
__global__ void csr_fill(const int* __restrict__ src, const int* __restrict__ dst,
                         int* __restrict__ cursor, int* __restrict__ col) {
    int e = blockIdx.x * blockDim.x + threadIdx.x;
    if (e < N_EDGES) {
        int pos = atomicAdd(&cursor[dst[e]], 1);
        col[pos] = src[e];
    }
}

// ---------------- x @ W1 -> A [N, HID] ----------------
__global__ void gemm_xw1(const float* __restrict__ x, const float* __restrict__ W1,
                         float* __restrict__ A) {
    __shared__ float xs[F_IN];
    int v = blockIdx.x;
    int j = threadIdx.x;
    if (j < F_IN) xs[j] = x[v * F_IN + j];
    __syncthreads();
    float acc = 0.f;
#pragma unroll
    for (int k = 0; k < F_IN; ++k) acc += xs[k] * W1[k * HID + j];
    A[v * HID + j] = acc;
}

// ---------------- gather-aggregate ----------------
template <bool RELU>
__global__ void aggregate(const float* __restrict__ A, const int* __restrict__ row_ptr,
                          const int* __restrict__ col, const float* __restrict__ dinv,
                          const float* __restrict__ bias, float* __restrict__ Bo) {
    int v = blockIdx.x;
    int f = threadIdx.x;                      // 0..127
    float dv = dinv[v];
    float acc = A[(size_t)v * HID + f] * dv * dv;   // self-loop
    int j   = row_ptr[v];
    int end = row_ptr[v + 1];
    for (; j + 1 < end; j += 2) {             // keep two A-row loads in flight
        int s0 = col[j], s1 = col[j + 1];
        float w0 = dinv[s0] * dv;
        float w1 = dinv[s1] * dv;
        float a0 = A[(size_t)s0 * HID + f];
        float a1 = A[(size_t)s1 * HID + f];
        acc += a0 * w0 + a1 * w1;
    }
    if (j < end) {
        int s = col[j];
        acc += A[(size_t)s * HID + f] * (dinv[s] * dv);
    }
    acc += bias[f];
    if (RELU) acc = fmaxf(acc, 0.f);
    Bo[(size_t)v * HID + f] = acc;
}

// ---------------- B @ W2 -> A [N, HID] ----------------
__global__ void gemm_w2(const float* __restrict__ Bm, const float* __restrict__ W2,
                        float* __restrict__ A) {
    __shared__ float row[HID];
    int v = blockIdx.x;
    int j = threadIdx.x;
    row[j] = Bm[v * HID + j];
    __syncthreads();
    float acc = 0.f;
#pragma unroll 8
    for (int k = 0; k < HID; ++k) acc += row[k] * W2[k * HID + j];
    A[v * HID + j] = acc;
}

// ---------------- mean-pool accumulate (b2 already folded into B) ----------------
__global__ void pool_accum(const float* __restrict__ B, const int* __restrict__ batch,
                           float* __restrict__ pooled, float* __restrict__ cnts) {
    int i = blockIdx.x * blockDim.x + threadIdx.x;
    if (i >= N_NODES * HID) return;
    int v = i >> 7;
    int f = i & (HID - 1);
    int g = batch[v];
    atomicAdd(&pooled[g * HID + f], B[i]);
    if (f == 0) atomicAdd(&cnts[g], 1.0f);
}

// ---------------- head: out = (pooled/cnt) @ Wlin + blin ----------------
__global__ void head_k(const float* __restrict__ pooled, const float* __restrict__ cnts,
                       const float* __restrict__ Wlin, const float* __restrict__ blin,
                       float* __restrict__ out) {
    int i = blockIdx.x * blockDim.x + threadIdx.x;
    if (i >= NUM_G * F_OUT) return;
    int g = i / F_OUT;
    int o = i - g * F_OUT;
    float c = cnts[g];
    c = c > 1.f ? c : 1.f;
    float acc = 0.f;
#pragma unroll 8
    for (int k = 0; k < HID; ++k) acc += pooled[g * HID + k] * Wlin[k * F_OUT + o];
    out[i] = acc / c + blin[o];
}

extern "C" void kernel_launch(void* const* d_in, const int* in_sizes, int n_in,
                              void* d_out, int out_size, void* d_ws, size_t ws_size,
                              hipStream_t stream) {
    const float* x    = (const float*)d_in[0];
    const int*   esrc = (const int*)  d_in[1];
    const int*   edst = (const int*)  d_in[2];
    const int*   batch= (const int*)  d_in[3];
    const float* W1   = (const float*)d_in[4];
    const float* b1   = (const float*)d_in[5];
    const float* W2   = (const float*)d_in[6];
    const float* b2   = (const float*)d_in[7];
    const float* Wlin = (const float*)d_in[8];
    const float* blin = (const float*)d_in[9];
    float* out = (float*)d_out;

    // workspace layout (~112 MB)
    char* p = (char*)d_ws;
    float* dinv    = (float*)p;   p += sizeof(float) * N_NODES;
    float* A       = (float*)p;   p += sizeof(float) * (size_t)N_NODES * HID;
    float* B       = (float*)p;   p += sizeof(float) * (size_t)N_NODES * HID;
    float* pooled  = (float*)p;   p += sizeof(float) * (size_t)NUM_G * HID;
    float* cnts    = (float*)p;   p += sizeof(float) * NUM_G;
    int*   cnt     = (int*)p;     p += sizeof(int) * N_NODES;       // reused as cursor
    int*   row_ptr = (int*)p;     p += sizeof(int) * (N_NODES + 1);
    int*   col     = (int*)p;     p += sizeof(int) * N_EDGES;
    int*   bsum    = (int*)p;     p += sizeof(int) * 128;

    const int nscan = (N_NODES + SCAN_B - 1) / SCAN_B;   // 98

    // ---- CSR build + normalization (used by both layers) ----
    hipMemsetAsync(cnt, 0, sizeof(int) * N_NODES, stream);
    count_deg<<<(N_EDGES + 255) / 256, 256, 0, stream>>>(edst, cnt);
    make_dinv<<<(N_NODES + 255) / 256, 256, 0, stream>>>(cnt, dinv);
    scan1<<<nscan, SCAN_B, 0, stream>>>(cnt, row_ptr, bsum);
    scan2<<<1, 64, 0, stream>>>(bsum, nscan);
    scan3<<<(N_NODES + 255) / 256, 256, 0, stream>>>(row_ptr, bsum, cnt);  // cnt -> cursor
    csr_fill<<<(N_EDGES + 255) / 256, 256, 0, stream>>>(esrc, edst, cnt, col);

    // ---- layer 1: A = x@W1 ; B = relu(aggregate(A) + b1) ----
    gemm_xw1<<<N_NODES, HID, 0, stream>>>(x, W1, A);
    aggregate<true><<<N_NODES, HID, 0, stream>>>(A, row_ptr, col, dinv, b1, B);

    // ---- layer 2: A = B@W2 ; B = aggregate(A) + b2 ----
    gemm_w2<<<N_NODES, HID, 0, stream>>>(B, W2, A);
    aggregate<false><<<N_NODES, HID, 0, stream>>>(A, row_ptr, col, dinv, b2, B);

    // ---- mean pool + head ----
    hipMemsetAsync(pooled, 0, sizeof(float) * ((size_t)NUM_G * HID + NUM_G), stream);
    pool_accum<<<(N_NODES * HID + 255) / 256, 256, 0, stream>>>(B, batch, pooled, cnts);
    head_k<<<(NUM_G * F_OUT + 255) / 256, 256, 0, stream>>>(pooled, cnts, Wlin, blin, out);
}

// Round 3
// 492.983 us; speedup vs baseline: 12.3340x; 1.7381x over previous
//
#include <hip/hip_runtime.h>

#define N_NODES 100000
#define N_EDGES 1600000
#define NUM_G   4096
#define HID     128
#define F_IN    11
#define F_OUT   19
#define SCAN_B  1024

// ---------------- degree count (in-degree on dst; self-loop added analytically) ----------------
__global__ void count_deg(const int* __restrict__ dst, int* __restrict__ cnt) {
    int e = blockIdx.x * blockDim.x + threadIdx.x;
    if (e < N_EDGES) atomicAdd(&cnt[dst[e]], 1);
}

__global__ void make_dinv(const int* __restrict__ cnt, float* __restrict__ dinv) {
    int i = blockIdx.x * blockDim.x + threadIdx.x;
    if (i < N_NODES) dinv[i] = rsqrtf(1.0f + (float)cnt[i]);   // +1 = self-loop
}

// ---------------- exclusive scan of cnt -> row_ptr ----------------
__global__ void scan1(const int* __restrict__ cnt, int* __restrict__ row_ptr,
                      int* __restrict__ bsum) {
    __shared__ int tmp[SCAN_B];
    int i = blockIdx.x * SCAN_B + threadIdx.x;
    int v = (i < N_NODES) ? cnt[i] : 0;
    tmp[threadIdx.x] = v;
    __syncthreads();
    for (int off = 1; off < SCAN_B; off <<= 1) {
        int t = (threadIdx.x >= (unsigned)off) ? tmp[threadIdx.x - off] : 0;
        __syncthreads();
        tmp[threadIdx.x] += t;
        __syncthreads();
    }
    if (i < N_NODES) row_ptr[i] = tmp[threadIdx.x] - v;        // block-local exclusive
    if (threadIdx.x == SCAN_B - 1) bsum[blockIdx.x] = tmp[SCAN_B - 1];
}

__global__ void scan2(int* __restrict__ bsum, int nb) {
    if (threadIdx.x == 0 && blockIdx.x == 0) {
        int run = 0;
        for (int i = 0; i < nb; ++i) { int t = bsum[i]; bsum[i] = run; run += t; }
    }
}

__global__ void scan3(int* __restrict__ row_ptr, const int* __restrict__ bsum,
                      int* __restrict__ cursor) {
    int i = blockIdx.x * blockDim.x + threadIdx.x;
    if (i < N_NODES) {
        int rp = row_ptr[i] + bsum[i / SCAN_B];
        row_ptr[i] = rp;
        cursor[i]  = rp;
    }
    if (i == 0) row_ptr[N_NODES] = N_EDGES;
}

// ---------------- CSR fill: col[pos] = src, bucketed by dst ----------------
__global__ void csr_fill(const int* __restrict__ src, const int* __restrict__ dst,
                         int* __restrict__ cursor, int* __restrict__ col) {
    int e = blockIdx.x * blockDim.x + threadIdx.x;
    if (e < N_EDGES) {
        int pos = atomicAdd(&cursor[dst[e]], 1);
        col[pos] = src[e];
    }
}

// ---------------- aggregate on raw x (11 feats): xa = N · x ----------------
// 16 threads per node (11 active), 256-thread block = 16 nodes.
__global__ void aggregate11(const float* __restrict__ x, const int* __restrict__ row_ptr,
                            const int* __restrict__ col, const float* __restrict__ dinv,
                            float* __restrict__ xa) {
    int tid = threadIdx.x;
    int v   = blockIdx.x * 16 + (tid >> 4);
    int f   = tid & 15;
    if (v >= N_NODES || f >= F_IN) return;
    float dv  = dinv[v];
    float acc = x[(size_t)v * F_IN + f] * dv * dv;      // self-loop
    int j = row_ptr[v], end = row_ptr[v + 1];
    for (; j + 1 < end; j += 2) {
        int s0 = col[j], s1 = col[j + 1];
        float w0 = dinv[s0] * dv, w1 = dinv[s1] * dv;
        float a0 = x[(size_t)s0 * F_IN + f];
        float a1 = x[(size_t)s1 * F_IN + f];
        acc += a0 * w0 + a1 * w1;
    }
    if (j < end) {
        int s = col[j];
        acc += x[(size_t)s * F_IN + f] * (dinv[s] * dv);
    }
    xa[(size_t)v * F_IN + f] = acc;
}

// ---------------- B = relu(xa @ W1 + b1) [N, HID] ----------------
__global__ void node_gemm1(const float* __restrict__ xa, const float* __restrict__ W1,
                           const float* __restrict__ b1, float* __restrict__ B) {
    __shared__ float xs[F_IN];
    int v = blockIdx.x;
    int j = threadIdx.x;
    if (j < F_IN) xs[j] = xa[(size_t)v * F_IN + j];
    __syncthreads();
    float acc = b1[j];
#pragma unroll
    for (int k = 0; k < F_IN; ++k) acc += xs[k] * W1[k * HID + j];
    B[(size_t)v * HID + j] = fmaxf(acc, 0.f);
}

// ---------------- aggregate128: C = N · B  (float4 lanes, 32 lanes/node) ----------------
__global__ void aggregate128(const float* __restrict__ B, const int* __restrict__ row_ptr,
                             const int* __restrict__ col, const float* __restrict__ dinv,
                             float* __restrict__ C) {
    int tid  = threadIdx.x;
    int v    = blockIdx.x * 8 + (tid >> 5);     // 256 threads = 8 nodes
    int lane = tid & 31;                         // float4 index 0..31
    const float4* B4 = (const float4*)B;
    float4*       C4 = (float4*)C;
    float dv = dinv[v];
    float4 a = B4[(size_t)v * 32 + lane];
    float4 acc;
    float dv2 = dv * dv;
    acc.x = a.x * dv2; acc.y = a.y * dv2; acc.z = a.z * dv2; acc.w = a.w * dv2;
    int j = row_ptr[v], end = row_ptr[v + 1];
    for (; j + 1 < end; j += 2) {
        int s0 = col[j], s1 = col[j + 1];
        float w0 = dinv[s0] * dv, w1 = dinv[s1] * dv;
        float4 a0 = B4[(size_t)s0 * 32 + lane];
        float4 a1 = B4[(size_t)s1 * 32 + lane];
        acc.x += a0.x * w0 + a1.x * w1;
        acc.y += a0.y * w0 + a1.y * w1;
        acc.z += a0.z * w0 + a1.z * w1;
        acc.w += a0.w * w0 + a1.w * w1;
    }
    if (j < end) {
        int s = col[j];
        float w = dinv[s] * dv;
        float4 a0 = B4[(size_t)s * 32 + lane];
        acc.x += a0.x * w; acc.y += a0.y * w; acc.z += a0.z * w; acc.w += a0.w * w;
    }
    C4[(size_t)v * 32 + lane] = acc;
}

// ---------------- fused pool + W2 + head: one block per graph ----------------
// batch sorted: binary-search node range, sum C rows, r = sum/cnt,
// t = r@W2 + b2 (if cnt>0), out = t@Wlin + blin.
__global__ void pool_head(const float* __restrict__ C, const int* __restrict__ batch,
                          const float* __restrict__ W2, const float* __restrict__ b2,
                          const float* __restrict__ Wlin, const float* __restrict__ blin,
                          float* __restrict__ out) {
    __shared__ float r[HID];
    __shared__ float t[HID];
    __shared__ int range[2];
    int g = blockIdx.x;
    int f = threadIdx.x;                 // 0..127
    if (f == 0) {
        int lo = 0, hi = N_NODES;
        while (lo < hi) { int m = (lo + hi) >> 1; if (batch[m] < g) lo = m + 1; else hi = m; }
        range[0] = lo;
        hi = N_NODES;
        while (lo < hi) { int m = (lo + hi) >> 1; if (batch[m] < g + 1) lo = m + 1; else hi = m; }
        range[1] = lo;
    }
    __syncthreads();
    int start = range[0], end = range[1];
    float acc = 0.f;
    for (int v = start; v < end; ++v) acc += C[(size_t)v * HID + f];
    float cntv = (float)(end - start);
    float inv  = (cntv > 0.f) ? 1.0f / cntv : 0.f;
    r[f] = acc * inv;
    __syncthreads();
    float bs = (cntv > 0.f) ? 1.0f : 0.f;
    float tj = b2[f] * bs;
#pragma unroll 8
    for (int k = 0; k < HID; ++k) tj += r[k] * W2[k * HID + f];
    t[f] = tj;
    __syncthreads();
    if (f < F_OUT) {
        float o = blin[f];
#pragma unroll 8
        for (int k = 0; k < HID; ++k) o += t[k] * Wlin[k * F_OUT + f];
        out[(size_t)g * F_OUT + f] = o;
    }
}

extern "C" void kernel_launch(void* const* d_in, const int* in_sizes, int n_in,
                              void* d_out, int out_size, void* d_ws, size_t ws_size,
                              hipStream_t stream) {
    const float* x    = (const float*)d_in[0];
    const int*   esrc = (const int*)  d_in[1];
    const int*   edst = (const int*)  d_in[2];
    const int*   batch= (const int*)  d_in[3];
    const float* W1   = (const float*)d_in[4];
    const float* b1   = (const float*)d_in[5];
    const float* W2   = (const float*)d_in[6];
    const float* b2   = (const float*)d_in[7];
    const float* Wlin = (const float*)d_in[8];
    const float* blin = (const float*)d_in[9];
    float* out = (float*)d_out;

    // workspace layout (~117 MB)
    char* p = (char*)d_ws;
    float* dinv    = (float*)p;   p += sizeof(float) * N_NODES;
    float* xa      = (float*)p;   p += sizeof(float) * (size_t)N_NODES * F_IN;
    float* B       = (float*)p;   p += sizeof(float) * (size_t)N_NODES * HID;
    float* C       = (float*)p;   p += sizeof(float) * (size_t)N_NODES * HID;
    int*   cnt     = (int*)p;     p += sizeof(int) * N_NODES;       // reused as cursor
    int*   row_ptr = (int*)p;     p += sizeof(int) * (N_NODES + 1);
    int*   col     = (int*)p;     p += sizeof(int) * N_EDGES;
    int*   bsum    = (int*)p;     p += sizeof(int) * 128;

    const int nscan = (N_NODES + SCAN_B - 1) / SCAN_B;   // 98

    // ---- CSR build + normalization ----
    hipMemsetAsync(cnt, 0, sizeof(int) * N_NODES, stream);
    count_deg<<<(N_EDGES + 255) / 256, 256, 0, stream>>>(edst, cnt);
    make_dinv<<<(N_NODES + 255) / 256, 256, 0, stream>>>(cnt, dinv);
    scan1<<<nscan, SCAN_B, 0, stream>>>(cnt, row_ptr, bsum);
    scan2<<<1, 64, 0, stream>>>(bsum, nscan);
    scan3<<<(N_NODES + 255) / 256, 256, 0, stream>>>(row_ptr, bsum, cnt);  // cnt -> cursor
    csr_fill<<<(N_EDGES + 255) / 256, 256, 0, stream>>>(esrc, edst, cnt, col);

    // ---- layer 1 (reordered): xa = N·x ; B = relu(xa@W1 + b1) ----
    aggregate11<<<(N_NODES + 15) / 16, 256, 0, stream>>>(x, row_ptr, col, dinv, xa);
    node_gemm1<<<N_NODES, HID, 0, stream>>>(xa, W1, b1, B);

    // ---- layer 2 (reordered): C = N·B ; (W2, b2 folded into head) ----
    aggregate128<<<N_NODES / 8, 256, 0, stream>>>(B, row_ptr, col, dinv, C);

    // ---- fused mean-pool + W2 + b2 + Wlin + blin ----
    pool_head<<<NUM_G, HID, 0, stream>>>(C, batch, W2, b2, Wlin, blin, out);
}

// Round 4
// 422.277 us; speedup vs baseline: 14.3992x; 1.1674x over previous
//
#include <hip/hip_runtime.h>

#define N_NODES 100000
#define N_EDGES 1600000
#define NUM_G   4096
#define HID     128
#define F_IN    11
#define F_OUT   19
#define SCAN_B  1024

// ---------------- helpers ----------------
__device__ inline unsigned short f32_to_bf16_rne(float x) {
    unsigned int u = __float_as_uint(x);
    u = (u + 0x7fffu + ((u >> 16) & 1u)) >> 16;
    return (unsigned short)u;
}

__device__ inline void bf16x8_to_f32(uint4 u, float f[8]) {
    f[0] = __uint_as_float(u.x << 16); f[1] = __uint_as_float(u.x & 0xffff0000u);
    f[2] = __uint_as_float(u.y << 16); f[3] = __uint_as_float(u.y & 0xffff0000u);
    f[4] = __uint_as_float(u.z << 16); f[5] = __uint_as_float(u.z & 0xffff0000u);
    f[6] = __uint_as_float(u.w << 16); f[7] = __uint_as_float(u.w & 0xffff0000u);
}

// ---------------- degree count ----------------
__global__ void count_deg(const int* __restrict__ dst, int* __restrict__ cnt) {
    int e = blockIdx.x * blockDim.x + threadIdx.x;
    if (e < N_EDGES) atomicAdd(&cnt[dst[e]], 1);
}

__global__ void make_dinv(const int* __restrict__ cnt, float* __restrict__ dinv) {
    int i = blockIdx.x * blockDim.x + threadIdx.x;
    if (i < N_NODES) dinv[i] = rsqrtf(1.0f + (float)cnt[i]);   // +1 = self-loop
}

// ---------------- exclusive scan of cnt -> row_ptr ----------------
__global__ void scan1(const int* __restrict__ cnt, int* __restrict__ row_ptr,
                      int* __restrict__ bsum) {
    __shared__ int tmp[SCAN_B];
    int i = blockIdx.x * SCAN_B + threadIdx.x;
    int v = (i < N_NODES) ? cnt[i] : 0;
    tmp[threadIdx.x] = v;
    __syncthreads();
    for (int off = 1; off < SCAN_B; off <<= 1) {
        int t = (threadIdx.x >= (unsigned)off) ? tmp[threadIdx.x - off] : 0;
        __syncthreads();
        tmp[threadIdx.x] += t;
        __syncthreads();
    }
    if (i < N_NODES) row_ptr[i] = tmp[threadIdx.x] - v;        // block-local exclusive
    if (threadIdx.x == SCAN_B - 1) bsum[blockIdx.x] = tmp[SCAN_B - 1];
}

// parallel single-block exclusive scan of bsum[0..nb), nb <= 128
__global__ void scan2p(int* __restrict__ bsum, int nb) {
    __shared__ int tmp[128];
    int i = threadIdx.x;
    int v = (i < nb) ? bsum[i] : 0;
    tmp[i] = v;
    __syncthreads();
    for (int off = 1; off < 128; off <<= 1) {
        int t = (i >= off) ? tmp[i - off] : 0;
        __syncthreads();
        tmp[i] += t;
        __syncthreads();
    }
    if (i < nb) bsum[i] = tmp[i] - v;
}

__global__ void scan3(int* __restrict__ row_ptr, const int* __restrict__ bsum,
                      int* __restrict__ cursor) {
    int i = blockIdx.x * blockDim.x + threadIdx.x;
    if (i < N_NODES) {
        int rp = row_ptr[i] + bsum[i / SCAN_B];
        row_ptr[i] = rp;
        cursor[i]  = rp;
    }
    if (i == 0) row_ptr[N_NODES] = N_EDGES;
}

// ---------------- CSR fill ----------------
__global__ void csr_fill(const int* __restrict__ src, const int* __restrict__ dst,
                         int* __restrict__ cursor, int* __restrict__ col) {
    int e = blockIdx.x * blockDim.x + threadIdx.x;
    if (e < N_EDGES) {
        int pos = atomicAdd(&cursor[dst[e]], 1);
        col[pos] = src[e];
    }
}

// ---------------- aggregate on raw x (11 feats): xa = N · x ----------------
__global__ void aggregate11(const float* __restrict__ x, const int* __restrict__ row_ptr,
                            const int* __restrict__ col, const float* __restrict__ dinv,
                            float* __restrict__ xa) {
    int tid = threadIdx.x;
    int v   = blockIdx.x * 16 + (tid >> 4);
    int f   = tid & 15;
    if (v >= N_NODES || f >= F_IN) return;
    float dv  = dinv[v];
    float acc = x[(size_t)v * F_IN + f] * dv * dv;      // self-loop
    int j = row_ptr[v], end = row_ptr[v + 1];
    for (; j + 3 < end; j += 4) {
        int s0 = col[j], s1 = col[j + 1], s2 = col[j + 2], s3 = col[j + 3];
        float w0 = dinv[s0] * dv, w1 = dinv[s1] * dv;
        float w2 = dinv[s2] * dv, w3 = dinv[s3] * dv;
        float a0 = x[(size_t)s0 * F_IN + f];
        float a1 = x[(size_t)s1 * F_IN + f];
        float a2 = x[(size_t)s2 * F_IN + f];
        float a3 = x[(size_t)s3 * F_IN + f];
        acc += a0 * w0 + a1 * w1 + a2 * w2 + a3 * w3;
    }
    for (; j < end; ++j) {
        int s = col[j];
        acc += x[(size_t)s * F_IN + f] * (dinv[s] * dv);
    }
    xa[(size_t)v * F_IN + f] = acc;
}

// ---------------- Bh = bf16(relu(xa @ W1 + b1)) [N, HID] ----------------
__global__ void node_gemm1(const float* __restrict__ xa, const float* __restrict__ W1,
                           const float* __restrict__ b1, unsigned short* __restrict__ Bh) {
    __shared__ float xs[F_IN];
    int v = blockIdx.x;
    int j = threadIdx.x;
    if (j < F_IN) xs[j] = xa[(size_t)v * F_IN + j];
    __syncthreads();
    float acc = b1[j];
#pragma unroll
    for (int k = 0; k < F_IN; ++k) acc += xs[k] * W1[k * HID + j];
    Bh[(size_t)v * HID + j] = f32_to_bf16_rne(fmaxf(acc, 0.f));
}

// ---------------- aggregate128 on bf16 rows: C = N · B ----------------
// 16 lanes/node, each lane owns 8 contiguous features (16 B load), unroll-4.
__global__ void aggregate128_bf16(const unsigned short* __restrict__ Bh,
                                  const int* __restrict__ row_ptr,
                                  const int* __restrict__ col,
                                  const float* __restrict__ dinv,
                                  float* __restrict__ C) {
    int tid  = threadIdx.x;
    int v    = blockIdx.x * 16 + (tid >> 4);     // 256 threads = 16 nodes
    int lane = tid & 15;                          // 8 feats per lane
    const uint4* B4 = (const uint4*)Bh;           // one row = 16 uint4
    float dv  = dinv[v];
    float dv2 = dv * dv;
    float acc[8], t[8];
    uint4 aself = B4[(size_t)v * 16 + lane];
    bf16x8_to_f32(aself, t);
#pragma unroll
    for (int k = 0; k < 8; ++k) acc[k] = t[k] * dv2;        // self-loop
    int j = row_ptr[v], end = row_ptr[v + 1];
    for (; j + 3 < end; j += 4) {
        int s0 = col[j], s1 = col[j + 1], s2 = col[j + 2], s3 = col[j + 3];
        uint4 a0 = B4[(size_t)s0 * 16 + lane];
        uint4 a1 = B4[(size_t)s1 * 16 + lane];
        uint4 a2 = B4[(size_t)s2 * 16 + lane];
        uint4 a3 = B4[(size_t)s3 * 16 + lane];
        float w0 = dinv[s0] * dv, w1 = dinv[s1] * dv;
        float w2 = dinv[s2] * dv, w3 = dinv[s3] * dv;
        float f0[8], f1[8], f2[8], f3[8];
        bf16x8_to_f32(a0, f0); bf16x8_to_f32(a1, f1);
        bf16x8_to_f32(a2, f2); bf16x8_to_f32(a3, f3);
#pragma unroll
        for (int k = 0; k < 8; ++k)
            acc[k] += f0[k] * w0 + f1[k] * w1 + f2[k] * w2 + f3[k] * w3;
    }
    for (; j < end; ++j) {
        int s = col[j];
        float w = dinv[s] * dv;
        uint4 a0 = B4[(size_t)s * 16 + lane];
        float f0[8];
        bf16x8_to_f32(a0, f0);
#pragma unroll
        for (int k = 0; k < 8; ++k) acc[k] += f0[k] * w;
    }
    float4* Co = (float4*)(C + (size_t)v * HID + lane * 8);
    Co[0] = make_float4(acc[0], acc[1], acc[2], acc[3]);
    Co[1] = make_float4(acc[4], acc[5], acc[6], acc[7]);
}

// ---------------- fused pool + W2 + head ----------------
__global__ void pool_head(const float* __restrict__ C, const int* __restrict__ batch,
                          const float* __restrict__ W2, const float* __restrict__ b2,
                          const float* __restrict__ Wlin, const float* __restrict__ blin,
                          float* __restrict__ out) {
    __shared__ float r[HID];
    __shared__ float t[HID];
    __shared__ int range[2];
    int g = blockIdx.x;
    int f = threadIdx.x;                 // 0..127
    if (f == 0) {
        int lo = 0, hi = N_NODES;
        while (lo < hi) { int m = (lo + hi) >> 1; if (batch[m] < g) lo = m + 1; else hi = m; }
        range[0] = lo;
        hi = N_NODES;
        while (lo < hi) { int m = (lo + hi) >> 1; if (batch[m] < g + 1) lo = m + 1; else hi = m; }
        range[1] = lo;
    }
    __syncthreads();
    int start = range[0], end = range[1];
    float acc = 0.f;
    for (int v = start; v < end; ++v) acc += C[(size_t)v * HID + f];
    float cntv = (float)(end - start);
    float inv  = (cntv > 0.f) ? 1.0f / cntv : 0.f;
    r[f] = acc * inv;
    __syncthreads();
    float bs = (cntv > 0.f) ? 1.0f : 0.f;
    float tj = b2[f] * bs;
#pragma unroll 8
    for (int k = 0; k < HID; ++k) tj += r[k] * W2[k * HID + f];
    t[f] = tj;
    __syncthreads();
    if (f < F_OUT) {
        float o = blin[f];
#pragma unroll 8
        for (int k = 0; k < HID; ++k) o += t[k] * Wlin[k * F_OUT + f];
        out[(size_t)g * F_OUT + f] = o;
    }
}

extern "C" void kernel_launch(void* const* d_in, const int* in_sizes, int n_in,
                              void* d_out, int out_size, void* d_ws, size_t ws_size,
                              hipStream_t stream) {
    const float* x    = (const float*)d_in[0];
    const int*   esrc = (const int*)  d_in[1];
    const int*   edst = (const int*)  d_in[2];
    const int*   batch= (const int*)  d_in[3];
    const float* W1   = (const float*)d_in[4];
    const float* b1   = (const float*)d_in[5];
    const float* W2   = (const float*)d_in[6];
    const float* b2   = (const float*)d_in[7];
    const float* Wlin = (const float*)d_in[8];
    const float* blin = (const float*)d_in[9];
    float* out = (float*)d_out;

    // workspace layout (~92 MB), all segments 16B-aligned
    char* p = (char*)d_ws;
    float*          dinv    = (float*)p;          p += sizeof(float) * N_NODES;
    float*          xa      = (float*)p;          p += sizeof(float) * (size_t)N_NODES * F_IN;
    unsigned short* Bh      = (unsigned short*)p; p += sizeof(unsigned short) * (size_t)N_NODES * HID;
    float*          C       = (float*)p;          p += sizeof(float) * (size_t)N_NODES * HID;
    int*            cnt     = (int*)p;            p += sizeof(int) * N_NODES;   // reused as cursor
    int*            row_ptr = (int*)p;            p += sizeof(int) * (N_NODES + 1);
    int*            col     = (int*)p;            p += sizeof(int) * N_EDGES;
    int*            bsum    = (int*)p;            p += sizeof(int) * 128;

    const int nscan = (N_NODES + SCAN_B - 1) / SCAN_B;   // 98

    // ---- CSR build + normalization ----
    hipMemsetAsync(cnt, 0, sizeof(int) * N_NODES, stream);
    count_deg<<<(N_EDGES + 255) / 256, 256, 0, stream>>>(edst, cnt);
    make_dinv<<<(N_NODES + 255) / 256, 256, 0, stream>>>(cnt, dinv);
    scan1<<<nscan, SCAN_B, 0, stream>>>(cnt, row_ptr, bsum);
    scan2p<<<1, 128, 0, stream>>>(bsum, nscan);
    scan3<<<(N_NODES + 255) / 256, 256, 0, stream>>>(row_ptr, bsum, cnt);  // cnt -> cursor
    csr_fill<<<(N_EDGES + 255) / 256, 256, 0, stream>>>(esrc, edst, cnt, col);

    // ---- layer 1 (reordered): xa = N·x ; Bh = bf16(relu(xa@W1 + b1)) ----
    aggregate11<<<(N_NODES + 15) / 16, 256, 0, stream>>>(x, row_ptr, col, dinv, xa);
    node_gemm1<<<N_NODES, HID, 0, stream>>>(xa, W1, b1, Bh);

    // ---- layer 2 (reordered): C = N·Bh ----
    aggregate128_bf16<<<(N_NODES + 15) / 16, 256, 0, stream>>>(Bh, row_ptr, col, dinv, C);

    // ---- fused mean-pool + W2 + b2 + Wlin + blin ----
    pool_head<<<NUM_G, HID, 0, stream>>>(C, batch, W2, b2, Wlin, blin, out);
}

// Round 5
// 301.637 us; speedup vs baseline: 20.1582x; 1.4000x over previous
//
#include <hip/hip_runtime.h>

#define N_NODES 100000
#define N_EDGES 1600000
#define NUM_G   4096
#define HID     128
#define F_IN    11
#define F_OUT   19

#define NB      256                  // dst buckets
#define KPB     391                  // nodes per bucket: 256*391 = 100096 >= 100000
#define P01_EPB 2048                 // edges per block in P0/P1

// ---------------- helpers ----------------
__device__ inline unsigned short f32_to_bf16_rne(float x) {
    unsigned int u = __float_as_uint(x);
    u = (u + 0x7fffu + ((u >> 16) & 1u)) >> 16;
    return (unsigned short)u;
}

__device__ inline void bf16x8_to_f32(uint4 u, float f[8]) {
    f[0] = __uint_as_float(u.x << 16); f[1] = __uint_as_float(u.x & 0xffff0000u);
    f[2] = __uint_as_float(u.y << 16); f[3] = __uint_as_float(u.y & 0xffff0000u);
    f[4] = __uint_as_float(u.z << 16); f[5] = __uint_as_float(u.z & 0xffff0000u);
    f[6] = __uint_as_float(u.w << 16); f[7] = __uint_as_float(u.w & 0xffff0000u);
}

// ---------------- P0: global bucket histogram (gh pre-zeroed) ----------------
__global__ void p0_hist(const int* __restrict__ dst, int* __restrict__ gh) {
    __shared__ int h[NB];
    h[threadIdx.x] = 0;
    __syncthreads();
    int b0 = blockIdx.x * P01_EPB;
#pragma unroll
    for (int k = 0; k < 8; ++k) {
        int e = b0 + k * 256 + threadIdx.x;
        if (e < N_EDGES) atomicAdd(&h[dst[e] / KPB], 1);
    }
    __syncthreads();
    int c = h[threadIdx.x];
    if (c) atomicAdd(&gh[threadIdx.x], c);
}

// ---------------- exclusive scan of gh -> bbase, bcur ----------------
__global__ void p0_scan(const int* __restrict__ gh, int* __restrict__ bbase,
                        int* __restrict__ bcur) {
    __shared__ int tmp[NB];
    int i = threadIdx.x;
    int v = gh[i];
    tmp[i] = v;
    __syncthreads();
    for (int off = 1; off < NB; off <<= 1) {
        int t = (i >= off) ? tmp[i - off] : 0;
        __syncthreads();
        tmp[i] += t;
        __syncthreads();
    }
    bbase[i] = tmp[i] - v;
    bcur[i]  = tmp[i] - v;
    if (i == NB - 1) bbase[NB] = N_EDGES;
}

// ---------------- P1: scatter (src,dst) into bucket regions ----------------
__global__ void p1_place(const int* __restrict__ src, const int* __restrict__ dst,
                         int* __restrict__ bcur, uint2* __restrict__ ebuf) {
    __shared__ int h[NB];
    __shared__ int base[NB];
    h[threadIdx.x] = 0;
    __syncthreads();
    int s[8], d[8], bn[8];
    int b0 = blockIdx.x * P01_EPB;
#pragma unroll
    for (int k = 0; k < 8; ++k) {
        int e = b0 + k * 256 + threadIdx.x;
        if (e < N_EDGES) { s[k] = src[e]; d[k] = dst[e]; bn[k] = d[k] / KPB; }
        else bn[k] = -1;
    }
#pragma unroll
    for (int k = 0; k < 8; ++k)
        if (bn[k] >= 0) atomicAdd(&h[bn[k]], 1);
    __syncthreads();
    {
        int c = h[threadIdx.x];
        base[threadIdx.x] = c ? atomicAdd(&bcur[threadIdx.x], c) : 0;
    }
    __syncthreads();
    h[threadIdx.x] = 0;            // reuse as local rank cursor
    __syncthreads();
#pragma unroll
    for (int k = 0; k < 8; ++k) {
        if (bn[k] >= 0) {
            int r = atomicAdd(&h[bn[k]], 1);
            ebuf[base[bn[k]] + r] = make_uint2((unsigned)s[k], (unsigned)d[k]);
        }
    }
}

// ---------------- P2: per-bucket count + scan + fill + dinv + row_ptr ----------------
__global__ void p2_build(const uint2* __restrict__ ebuf, const int* __restrict__ bbase,
                         int* __restrict__ row_ptr, int* __restrict__ col,
                         float* __restrict__ dinv) {
    __shared__ int hist[512];
    __shared__ int rp[512];
    int b  = blockIdx.x;
    int t  = threadIdx.x;
    int dbase = b * KPB;
    int nd = N_NODES - dbase; if (nd > KPB) nd = KPB;
    hist[t] = 0;
    __syncthreads();
    int e0 = bbase[b], e1 = bbase[b + 1];
    for (int e = e0 + t; e < e1; e += 512)
        atomicAdd(&hist[ebuf[e].y - dbase], 1);
    __syncthreads();
    int v = hist[t];
    rp[t] = v;
    __syncthreads();
    for (int off = 1; off < 512; off <<= 1) {
        int x = (t >= off) ? rp[t - off] : 0;
        __syncthreads();
        rp[t] += x;
        __syncthreads();
    }
    int excl = rp[t] - v;
    if (t < nd) {
        row_ptr[dbase + t] = e0 + excl;
        dinv[dbase + t]    = rsqrtf(1.0f + (float)v);
    }
    if (b == NB - 1 && t == 0) row_ptr[N_NODES] = N_EDGES;
    __syncthreads();
    hist[t] = e0 + excl;           // reuse as col-position cursor
    __syncthreads();
    for (int e = e0 + t; e < e1; e += 512) {
        uint2 ed = ebuf[e];
        int pos = atomicAdd(&hist[ed.y - dbase], 1);
        col[pos] = (int)ed.x;
    }
}

// ---------------- aggregate on raw x (11 feats): xa = N · x ----------------
__global__ void aggregate11(const float* __restrict__ x, const int* __restrict__ row_ptr,
                            const int* __restrict__ col, const float* __restrict__ dinv,
                            float* __restrict__ xa) {
    int tid = threadIdx.x;
    int v   = blockIdx.x * 16 + (tid >> 4);
    int f   = tid & 15;
    if (f >= F_IN) return;
    float dv  = dinv[v];
    float acc = x[(size_t)v * F_IN + f] * dv * dv;      // self-loop
    int j = row_ptr[v], end = row_ptr[v + 1];
    for (; j + 3 < end; j += 4) {
        int s0 = col[j], s1 = col[j + 1], s2 = col[j + 2], s3 = col[j + 3];
        float w0 = dinv[s0] * dv, w1 = dinv[s1] * dv;
        float w2 = dinv[s2] * dv, w3 = dinv[s3] * dv;
        float a0 = x[(size_t)s0 * F_IN + f];
        float a1 = x[(size_t)s1 * F_IN + f];
        float a2 = x[(size_t)s2 * F_IN + f];
        float a3 = x[(size_t)s3 * F_IN + f];
        acc += a0 * w0 + a1 * w1 + a2 * w2 + a3 * w3;
    }
    for (; j < end; ++j) {
        int s = col[j];
        acc += x[(size_t)s * F_IN + f] * (dinv[s] * dv);
    }
    xa[(size_t)v * F_IN + f] = acc;
}

// ---------------- Bh = bf16(relu(xa @ W1 + b1)) [N, HID] ----------------
__global__ void node_gemm1(const float* __restrict__ xa, const float* __restrict__ W1,
                           const float* __restrict__ b1, unsigned short* __restrict__ Bh) {
    __shared__ float xs[F_IN];
    int v = blockIdx.x;
    int j = threadIdx.x;
    if (j < F_IN) xs[j] = xa[(size_t)v * F_IN + j];
    __syncthreads();
    float acc = b1[j];
#pragma unroll
    for (int k = 0; k < F_IN; ++k) acc += xs[k] * W1[k * HID + j];
    Bh[(size_t)v * HID + j] = f32_to_bf16_rne(fmaxf(acc, 0.f));
}

// ---------------- aggregate128 on bf16 rows: C = N · B ----------------
__global__ void aggregate128_bf16(const unsigned short* __restrict__ Bh,
                                  const int* __restrict__ row_ptr,
                                  const int* __restrict__ col,
                                  const float* __restrict__ dinv,
                                  float* __restrict__ C) {
    int tid  = threadIdx.x;
    int v    = blockIdx.x * 16 + (tid >> 4);     // 256 threads = 16 nodes
    int lane = tid & 15;                          // 8 feats per lane
    const uint4* B4 = (const uint4*)Bh;           // one row = 16 uint4
    float dv  = dinv[v];
    float dv2 = dv * dv;
    float acc[8], t[8];
    uint4 aself = B4[(size_t)v * 16 + lane];
    bf16x8_to_f32(aself, t);
#pragma unroll
    for (int k = 0; k < 8; ++k) acc[k] = t[k] * dv2;        // self-loop
    int j = row_ptr[v], end = row_ptr[v + 1];
    for (; j + 3 < end; j += 4) {
        int s0 = col[j], s1 = col[j + 1], s2 = col[j + 2], s3 = col[j + 3];
        uint4 a0 = B4[(size_t)s0 * 16 + lane];
        uint4 a1 = B4[(size_t)s1 * 16 + lane];
        uint4 a2 = B4[(size_t)s2 * 16 + lane];
        uint4 a3 = B4[(size_t)s3 * 16 + lane];
        float w0 = dinv[s0] * dv, w1 = dinv[s1] * dv;
        float w2 = dinv[s2] * dv, w3 = dinv[s3] * dv;
        float f0[8], f1[8], f2[8], f3[8];
        bf16x8_to_f32(a0, f0); bf16x8_to_f32(a1, f1);
        bf16x8_to_f32(a2, f2); bf16x8_to_f32(a3, f3);
#pragma unroll
        for (int k = 0; k < 8; ++k)
            acc[k] += f0[k] * w0 + f1[k] * w1 + f2[k] * w2 + f3[k] * w3;
    }
    for (; j < end; ++j) {
        int s = col[j];
        float w = dinv[s] * dv;
        uint4 a0 = B4[(size_t)s * 16 + lane];
        float f0[8];
        bf16x8_to_f32(a0, f0);
#pragma unroll
        for (int k = 0; k < 8; ++k) acc[k] += f0[k] * w;
    }
    float4* Co = (float4*)(C + (size_t)v * HID + lane * 8);
    Co[0] = make_float4(acc[0], acc[1], acc[2], acc[3]);
    Co[1] = make_float4(acc[4], acc[5], acc[6], acc[7]);
}

// ---------------- fused pool + W2 + head ----------------
__global__ void pool_head(const float* __restrict__ C, const int* __restrict__ batch,
                          const float* __restrict__ W2, const float* __restrict__ b2,
                          const float* __restrict__ Wlin, const float* __restrict__ blin,
                          float* __restrict__ out) {
    __shared__ float r[HID];
    __shared__ float t[HID];
    __shared__ int range[2];
    int g = blockIdx.x;
    int f = threadIdx.x;                 // 0..127
    if (f == 0) {
        int lo = 0, hi = N_NODES;
        while (lo < hi) { int m = (lo + hi) >> 1; if (batch[m] < g) lo = m + 1; else hi = m; }
        range[0] = lo;
        hi = N_NODES;
        while (lo < hi) { int m = (lo + hi) >> 1; if (batch[m] < g + 1) lo = m + 1; else hi = m; }
        range[1] = lo;
    }
    __syncthreads();
    int start = range[0], end = range[1];
    float acc = 0.f;
    for (int v = start; v < end; ++v) acc += C[(size_t)v * HID + f];
    float cntv = (float)(end - start);
    float inv  = (cntv > 0.f) ? 1.0f / cntv : 0.f;
    r[f] = acc * inv;
    __syncthreads();
    float bs = (cntv > 0.f) ? 1.0f : 0.f;
    float tj = b2[f] * bs;
#pragma unroll 8
    for (int k = 0; k < HID; ++k) tj += r[k] * W2[k * HID + f];
    t[f] = tj;
    __syncthreads();
    if (f < F_OUT) {
        float o = blin[f];
#pragma unroll 8
        for (int k = 0; k < HID; ++k) o += t[k] * Wlin[k * F_OUT + f];
        out[(size_t)g * F_OUT + f] = o;
    }
}

extern "C" void kernel_launch(void* const* d_in, const int* in_sizes, int n_in,
                              void* d_out, int out_size, void* d_ws, size_t ws_size,
                              hipStream_t stream) {
    const float* x    = (const float*)d_in[0];
    const int*   esrc = (const int*)  d_in[1];
    const int*   edst = (const int*)  d_in[2];
    const int*   batch= (const int*)  d_in[3];
    const float* W1   = (const float*)d_in[4];
    const float* b1   = (const float*)d_in[5];
    const float* W2   = (const float*)d_in[6];
    const float* b2   = (const float*)d_in[7];
    const float* Wlin = (const float*)d_in[8];
    const float* blin = (const float*)d_in[9];
    float* out = (float*)d_out;

    // workspace layout (~101 MB), all segments 16B-aligned
    char* p = (char*)d_ws;
    float*          dinv    = (float*)p;          p += sizeof(float) * N_NODES;
    float*          xa      = (float*)p;          p += sizeof(float) * (size_t)N_NODES * F_IN;
    unsigned short* Bh      = (unsigned short*)p; p += sizeof(unsigned short) * (size_t)N_NODES * HID;
    float*          C       = (float*)p;          p += sizeof(float) * (size_t)N_NODES * HID;
    uint2*          ebuf    = (uint2*)p;          p += sizeof(uint2) * (size_t)N_EDGES;
    int*            row_ptr = (int*)p;            p += sizeof(int) * (N_NODES + 4);
    int*            col     = (int*)p;            p += sizeof(int) * N_EDGES;
    int*            gh      = (int*)p;            p += sizeof(int) * NB;
    int*            bbase   = (int*)p;            p += sizeof(int) * (NB + 4);
    int*            bcur    = (int*)p;            p += sizeof(int) * NB;

    const int nblk_e = (N_EDGES + P01_EPB - 1) / P01_EPB;   // 782

    // ---- CSR build (bucketed counting sort) + dinv ----
    hipMemsetAsync(gh, 0, sizeof(int) * NB, stream);
    p0_hist <<<nblk_e, 256, 0, stream>>>(edst, gh);
    p0_scan <<<1, NB, 0, stream>>>(gh, bbase, bcur);
    p1_place<<<nblk_e, 256, 0, stream>>>(esrc, edst, bcur, ebuf);
    p2_build<<<NB, 512, 0, stream>>>(ebuf, bbase, row_ptr, col, dinv);

    // ---- layer 1 (reordered): xa = N·x ; Bh = bf16(relu(xa@W1 + b1)) ----
    aggregate11<<<(N_NODES + 15) / 16, 256, 0, stream>>>(x, row_ptr, col, dinv, xa);
    node_gemm1<<<N_NODES, HID, 0, stream>>>(xa, W1, b1, Bh);

    // ---- layer 2 (reordered): C = N·Bh ----
    aggregate128_bf16<<<(N_NODES + 15) / 16, 256, 0, stream>>>(Bh, row_ptr, col, dinv, C);

    // ---- fused mean-pool + W2 + b2 + Wlin + blin ----
    pool_head<<<NUM_G, HID, 0, stream>>>(C, batch, W2, b2, Wlin, blin, out);
}